// Round 15
// baseline (926.745 us; speedup 1.0000x reference)
//
#include <hip/hip_runtime.h>
#include <hip/hip_bf16.h>

#define Bdim 32
#define Ndim 4096
#define Cdim 768
#define Kdim 64

typedef float f32x4 __attribute__((ext_vector_type(4)));
typedef short s16x8 __attribute__((ext_vector_type(8)));
typedef __bf16 bf16x8 __attribute__((ext_vector_type(8)));

__device__ __forceinline__ short f2bf(float f) {
  return __builtin_bit_cast(short, (__bf16)f);   // hw RNE cvt
}
__device__ __forceinline__ float bf2f(short s) {
  return (float)__builtin_bit_cast(__bf16, s);
}
__device__ __forceinline__ f32x4 MFMA(s16x8 a, s16x8 b, f32x4 c) {
  return __builtin_amdgcn_mfma_f32_16x16x32_bf16(
      __builtin_bit_cast(bf16x8, a), __builtin_bit_cast(bf16x8, b), c, 0, 0, 0);
}

// ---------------- k0: W fp32 -> bf16 (fragment order) + zero finisher counters -----
__global__ void k0_wcvt(const float* __restrict__ W, short* __restrict__ Wr,
                        int* __restrict__ cnt) {
  int idx = blockIdx.x * 256 + threadIdx.x;  // chunk of 8 elems; K*C/8 = 6144
  if (idx < 512) cnt[idx] = 0;               // re-arm (covers 0xAA poison too)
  if (idx >= Kdim * Cdim / 8) return;
  int k = idx / (Cdim / 8), c8 = idx % (Cdim / 8);
  int cs = c8 >> 2, g = c8 & 3;
  int t = k >> 4, i = k & 15;
  const float* src = W + (size_t)k * Cdim + c8 * 8;
  s16x8 v;
#pragma unroll
  for (int e = 0; e < 8; ++e) v[e] = f2bf(src[e]);
  *(s16x8*)(Wr + ((((size_t)cs * 4 + t) * 4 + g) * 16 + i) * 8) = v;
}

// ---------------- k1: P = bf16(exp(x @ W^T)) (exotic layout) + tile sums ----------
// (R12-proven form: 24 loads in flight per group, exp folded into epilogue.)
__global__ __launch_bounds__(256) void k1_logits(
    const float* __restrict__ x, const short* __restrict__ Wr,
    short* __restrict__ P, float* __restrict__ ps) {
  const int blk = blockIdx.x;
  const int b = blk >> 6;          // 64 ntiles per batch
  const int ntile = blk & 63;      // 64 rows per tile
  const int tid = threadIdx.x;
  const int w = tid >> 6;
  const int l = tid & 63;
  const int g = l >> 4, i = l & 15;

  const float* xrow = x + (size_t)(b * Ndim + ntile * 64 + w * 16 + i) * Cdim;
  f32x4 acc[4] = {};

  for (int grp = 0; grp < 6; ++grp) {   // 6 groups x (4 cs-steps of K=32)
    const int cbase = grp * 128 + g * 8;
    f32x4 xv[8];
    s16x8 wv[4][4];
#pragma unroll
    for (int s = 0; s < 4; ++s) {
      const f32x4* ap = (const f32x4*)(xrow + cbase + s * 32);
      xv[2 * s] = ap[0];
      xv[2 * s + 1] = ap[1];
    }
#pragma unroll
    for (int s = 0; s < 4; ++s) {
#pragma unroll
      for (int t = 0; t < 4; ++t) {
        wv[s][t] = *(const s16x8*)(
            Wr + ((((size_t)(grp * 4 + s) * 4 + t) * 4 + g) * 16 + i) * 8);
      }
    }
#pragma unroll
    for (int s = 0; s < 4; ++s) {
      s16x8 af;
#pragma unroll
      for (int e = 0; e < 4; ++e) af[e] = f2bf(xv[2 * s][e]);
#pragma unroll
      for (int e = 0; e < 4; ++e) af[4 + e] = f2bf(xv[2 * s + 1][e]);
#pragma unroll
      for (int t = 0; t < 4; ++t) acc[t] = MFMA(af, wv[s][t], acc[t]);
    }
  }

  // epilogue: P = bf16(exp(logit)), store + per-tile sum (no max needed)
  short* Pb = P + (size_t)b * (Ndim * Kdim);
  float sv[4];
#pragma unroll
  for (int t = 0; t < 4; ++t) {
    sv[t] = 0.f;
#pragma unroll
    for (int r = 0; r < 4; ++r) {
      int n = ntile * 64 + w * 16 + g * 4 + r;  // D row = 4*(l>>4)+reg
      int k = t * 16 + i;                       // D col = l&15
      short hv = f2bf(__expf(acc[t][r]));
      Pb[(n >> 3) * 512 + k * 8 + (n & 7)] = hv;
      sv[t] += bf2f(hv);                        // sum the ROUNDED values
    }
    sv[t] += __shfl_xor(sv[t], 16);
    sv[t] += __shfl_xor(sv[t], 32);
  }
  __shared__ float rs[4][4][16];  // [w][t][i]
  if (g == 0) {
#pragma unroll
    for (int t = 0; t < 4; ++t) rs[w][t][i] = sv[t];
  }
  __syncthreads();
  if (w == 0 && g == 0) {
#pragma unroll
    for (int t = 0; t < 4; ++t) {
      float S = rs[0][t][i] + rs[1][t][i] + rs[2][t][i] + rs[3][t][i];
      ps[((size_t)b * 64 + ntile) * 64 + t * 16 + i] = S;
    }
  }
}

// ---------------- k3: partials + fused last-block finisher (old k2b + k4) ----------
// Core loop = R14-proven (dbuf LDS, one soft barrier/chunk). After writing its
// q-partial, each block bumps cnt[b*16+ct]; the 4th block computes invd from
// psum and writes the final out slice (deterministic values: fixed sum order).
#define CT 48    // c-columns per block
#define NCH 128  // n rows staged per chunk
#define NQ 4     // n-splits
#define BUFO (CT * 128)  // shorts per LDS buffer
#define QS (Bdim * Kdim * Cdim)  // floats per q-slice of part
__device__ __forceinline__ int swz(int c) {
  return ((((c >> 3) ^ c) & 7) << 4);  // byte-XOR within a 256B row
}
__global__ __launch_bounds__(256) void k3_tokens(
    const float* __restrict__ x, const short* __restrict__ P,
    const float* __restrict__ psum, float* __restrict__ part,
    int* __restrict__ cnt, float* __restrict__ out) {
  __shared__ short xs[2 * BUFO];  // 2 x (CT rows x 256 bytes)
  char* xsb = (char*)xs;
  const int blk = blockIdx.x;
  const int q = blk & 3;
  const int ct = (blk >> 2) & 15;
  const int b = blk >> 6;
  const int tid = threadIdx.x;
  const int w = tid >> 6, l = tid & 63, g = l >> 4, i = l & 15;

  const float* xb = x + (size_t)b * Ndim * Cdim;
  const short* Pb = P + (size_t)b * (Ndim * Kdim);

  f32x4 acc[3] = {};

#define LOADX(ch, buf)                                                        \
  do {                                                                        \
    const int n0_ = (ch) * NCH;                                               \
    _Pragma("unroll") for (int uu = 0; uu < 3; ++uu) {                        \
      int u_ = tid + uu * 256;                                                \
      int n_ = u_ / 6, c8_ = u_ % 6;                                          \
      const f32x4* src_ =                                                     \
          (const f32x4*)(xb + (size_t)(n0_ + n_) * Cdim + ct * CT + c8_ * 8); \
      buf[uu][0] = src_[0];                                                   \
      buf[uu][1] = src_[1];                                                   \
    }                                                                         \
  } while (0)

#define LOADL(ch, lvb)                                                        \
  do {                                                                        \
    const int nb8_ = (ch) * 16;                                               \
    _Pragma("unroll") for (int ns = 0; ns < 4; ++ns) {                        \
      lvb[ns] = *(const s16x8*)(Pb + (size_t)(nb8_ + ns * 4 + g) * 512 +      \
                                (w * 16 + i) * 8);                            \
    }                                                                         \
  } while (0)

#define STORELDS(base, buf)                                                   \
  do {                                                                        \
    _Pragma("unroll") for (int uu = 0; uu < 3; ++uu) {                        \
      int u_ = tid + uu * 256;                                                \
      int n_ = u_ / 6, c8_ = u_ % 6;                                          \
      _Pragma("unroll") for (int e = 0; e < 8; ++e) {                         \
        int c_ = c8_ * 8 + e;                                                 \
        float fv_ = (e < 4) ? buf[uu][0][e] : buf[uu][1][e - 4];              \
        *(short*)(xsb + (base) + c_ * 256 + ((2 * n_) ^ swz(c_))) = f2bf(fv_);\
      }                                                                       \
    }                                                                         \
  } while (0)

#define COMPUTE(base, lvb)                                                    \
  do {                                                                        \
    _Pragma("unroll") for (int ns = 0; ns < 4; ++ns) {                        \
      _Pragma("unroll") for (int cs = 0; cs < 3; ++cs) {                      \
        const int c_ = cs * 16 + i;                                           \
        s16x8 bfr_ = *(const s16x8*)(xsb + (base) + c_ * 256 +                \
                                     ((ns * 64 + g * 16) ^ swz(c_)));         \
        acc[cs] = MFMA(lvb[ns], bfr_, acc[cs]);                               \
      }                                                                       \
    }                                                                         \
  } while (0)

#define SOFT_BARRIER()                                                        \
  do {                                                                        \
    asm volatile("s_waitcnt lgkmcnt(0)" ::: "memory");                        \
    __builtin_amdgcn_s_barrier();                                             \
    __builtin_amdgcn_sched_barrier(0);                                        \
  } while (0)

  f32x4 stA[3][2], stB[3][2];
  s16x8 lvA[4], lvB[4];

  const int ch0 = q * 8;  // 8 chunks of 128 n per block
  LOADX(ch0, stA);
  LOADL(ch0, lvA);
  LOADX(ch0 + 1, stB);
  LOADL(ch0 + 1, lvB);
  STORELDS(0, stA);
  SOFT_BARRIER();

  for (int c = 0; c < 8; c += 2) {
    if (c + 2 < 8) LOADX(ch0 + c + 2, stA);
    STORELDS(BUFO * 2, stB);
    COMPUTE(0, lvA);
    if (c + 2 < 8) LOADL(ch0 + c + 2, lvA);
    SOFT_BARRIER();
    if (c + 3 < 8) LOADX(ch0 + c + 3, stB);
    if (c + 2 < 8) STORELDS(0, stA);
    COMPUTE(BUFO * 2, lvB);
    if (c + 3 < 8) LOADL(ch0 + c + 3, lvB);
    SOFT_BARRIER();
  }

  // ---- write own partial slice ----
  float* pb = part + (size_t)q * QS + (size_t)b * (Kdim * Cdim);
#pragma unroll
  for (int r = 0; r < 4; ++r) {
    const int k = w * 16 + g * 4 + r;
#pragma unroll
    for (int cs = 0; cs < 3; ++cs) {
      pb[(size_t)k * Cdim + ct * CT + cs * 16 + i] = acc[cs][r];
    }
  }

  // ---- last-block-per-(b,ct) finisher: invd (old k2b) + out slice (old k4) ----
  __threadfence();                      // release: flush part to LLC
  __shared__ int lastf;
  if (tid == 0) {
    int old = atomicAdd(&cnt[b * 16 + ct], 1);
    lastf = (old == 3);
    if (old == 3) atomicExch(&cnt[b * 16 + ct], 0);  // re-arm for next replay
  }
  __syncthreads();
  if (!lastf) return;
  __threadfence();                      // acquire: invalidate L2 (cross-XCD reads)

  const int kk = tid & 63, nt4 = tid >> 6;
  float S = 0.f;
#pragma unroll
  for (int j = 0; j < 16; ++j)
    S += psum[((size_t)b * 64 + nt4 * 16 + j) * 64 + kk];
  __shared__ float ssum[4][64];
  __shared__ float ivs[64];
  ssum[nt4][kk] = S;
  __syncthreads();
  if (nt4 == 0)
    ivs[kk] = 1.f / (ssum[0][kk] + ssum[1][kk] + ssum[2][kk] + ssum[3][kk]);
  __syncthreads();

  const float* p0 = part + (size_t)b * (Kdim * Cdim) + ct * CT;
  float* ob = out + (size_t)b * (Kdim * Cdim) + ct * CT;
#pragma unroll
  for (int j = 0; j < 12; ++j) {
    int flat = tid + j * 256;           // 0..3071 = 64 k x 48 c
    int k2 = flat / 48, cc = flat % 48;
    size_t off = (size_t)k2 * Cdim + cc;
    float s = p0[off] + p0[off + QS] + p0[off + 2 * (size_t)QS] +
              p0[off + 3 * (size_t)QS];
    ob[off] = s * ivs[k2];
  }
#undef LOADX
#undef LOADL
#undef STORELDS
#undef COMPUTE
#undef SOFT_BARRIER
}

extern "C" void kernel_launch(void* const* d_in, const int* in_sizes, int n_in,
                              void* d_out, int out_size, void* d_ws, size_t ws_size,
                              hipStream_t stream) {
  const float* x = (const float*)d_in[0];
  const float* W = (const float*)d_in[1];
  float* out = (float*)d_out;
  char* ws = (char*)d_ws;

  short* Wb = (short*)ws;                                   // 96 KB (pad 128K)
  short* P = (short*)(ws + (1 << 17));                      // 16 MB bf16 exp-logits
  char* after = ws + (1 << 17) + (size_t)Bdim * Ndim * Kdim * 2;
  float* psum = (float*)after;                              // [32][64][64] tile sums
  int* cnt = (int*)(psum + Bdim * 64 * 64);                 // 512 finisher counters
  float* part = (float*)(cnt + 1024);                       // [4][32][64][768] fp32

  hipLaunchKernelGGL(k0_wcvt, dim3(24), dim3(256), 0, stream, W, Wb, cnt);
  hipLaunchKernelGGL(k1_logits, dim3(Bdim * 64), dim3(256), 0, stream, x, Wb, P, psum);
  hipLaunchKernelGGL(k3_tokens, dim3(Bdim * 16 * NQ), dim3(256), 0, stream,
                     x, P, psum, part, cnt, out);
}

// Round 16
// 220.235 us; speedup vs baseline: 4.2080x; 4.2080x over previous
//
#include <hip/hip_runtime.h>
#include <hip/hip_bf16.h>

#define Bdim 32
#define Ndim 4096
#define Cdim 768
#define Kdim 64

typedef float f32x4 __attribute__((ext_vector_type(4)));
typedef short s16x8 __attribute__((ext_vector_type(8)));
typedef __bf16 bf16x8 __attribute__((ext_vector_type(8)));

__device__ __forceinline__ short f2bf(float f) {
  return __builtin_bit_cast(short, (__bf16)f);   // hw RNE cvt
}
__device__ __forceinline__ float bf2f(short s) {
  return (float)__builtin_bit_cast(__bf16, s);
}
__device__ __forceinline__ f32x4 MFMA(s16x8 a, s16x8 b, f32x4 c) {
  return __builtin_amdgcn_mfma_f32_16x16x32_bf16(
      __builtin_bit_cast(bf16x8, a), __builtin_bit_cast(bf16x8, b), c, 0, 0, 0);
}

// ---------------- k0: W fp32 -> bf16, fragment-order layout ----------------
__global__ void k0_wcvt(const float* __restrict__ W, short* __restrict__ Wr) {
  int idx = blockIdx.x * 256 + threadIdx.x;  // chunk of 8 elems; K*C/8 = 6144
  if (idx >= Kdim * Cdim / 8) return;
  int k = idx / (Cdim / 8), c8 = idx % (Cdim / 8);
  int cs = c8 >> 2, g = c8 & 3;
  int t = k >> 4, i = k & 15;
  const float* src = W + (size_t)k * Cdim + c8 * 8;
  s16x8 v;
#pragma unroll
  for (int e = 0; e < 8; ++e) v[e] = f2bf(src[e]);
  *(s16x8*)(Wr + ((((size_t)cs * 4 + t) * 4 + g) * 16 + i) * 8) = v;
}

// ---------------- k1: P = bf16(exp(x @ W^T)) (exotic layout) + tile sums ----------
// (R12-proven form: 24 loads in flight per group, exp folded into epilogue.)
__global__ __launch_bounds__(256) void k1_logits(
    const float* __restrict__ x, const short* __restrict__ Wr,
    short* __restrict__ P, float* __restrict__ ps) {
  const int blk = blockIdx.x;
  const int b = blk >> 6;          // 64 ntiles per batch
  const int ntile = blk & 63;      // 64 rows per tile
  const int tid = threadIdx.x;
  const int w = tid >> 6;
  const int l = tid & 63;
  const int g = l >> 4, i = l & 15;

  const float* xrow = x + (size_t)(b * Ndim + ntile * 64 + w * 16 + i) * Cdim;
  f32x4 acc[4] = {};

  for (int grp = 0; grp < 6; ++grp) {   // 6 groups x (4 cs-steps of K=32)
    const int cbase = grp * 128 + g * 8;
    f32x4 xv[8];
    s16x8 wv[4][4];
#pragma unroll
    for (int s = 0; s < 4; ++s) {
      const f32x4* ap = (const f32x4*)(xrow + cbase + s * 32);
      xv[2 * s] = ap[0];
      xv[2 * s + 1] = ap[1];
    }
#pragma unroll
    for (int s = 0; s < 4; ++s) {
#pragma unroll
      for (int t = 0; t < 4; ++t) {
        wv[s][t] = *(const s16x8*)(
            Wr + ((((size_t)(grp * 4 + s) * 4 + t) * 4 + g) * 16 + i) * 8);
      }
    }
#pragma unroll
    for (int s = 0; s < 4; ++s) {
      s16x8 af;
#pragma unroll
      for (int e = 0; e < 4; ++e) af[e] = f2bf(xv[2 * s][e]);
#pragma unroll
      for (int e = 0; e < 4; ++e) af[4 + e] = f2bf(xv[2 * s + 1][e]);
#pragma unroll
      for (int t = 0; t < 4; ++t) acc[t] = MFMA(af, wv[s][t], acc[t]);
    }
  }

  // epilogue: P = bf16(exp(logit)), store + per-tile sum (no max needed)
  short* Pb = P + (size_t)b * (Ndim * Kdim);
  float sv[4];
#pragma unroll
  for (int t = 0; t < 4; ++t) {
    sv[t] = 0.f;
#pragma unroll
    for (int r = 0; r < 4; ++r) {
      int n = ntile * 64 + w * 16 + g * 4 + r;  // D row = 4*(l>>4)+reg
      int k = t * 16 + i;                       // D col = l&15
      short hv = f2bf(__expf(acc[t][r]));
      Pb[(n >> 3) * 512 + k * 8 + (n & 7)] = hv;
      sv[t] += bf2f(hv);                        // sum the ROUNDED values
    }
    sv[t] += __shfl_xor(sv[t], 16);
    sv[t] += __shfl_xor(sv[t], 32);
  }
  __shared__ float rs[4][4][16];  // [w][t][i]
  if (g == 0) {
#pragma unroll
    for (int t = 0; t < 4; ++t) rs[w][t][i] = sv[t];
  }
  __syncthreads();
  if (w == 0 && g == 0) {
#pragma unroll
    for (int t = 0; t < 4; ++t) {
      float S = rs[0][t][i] + rs[1][t][i] + rs[2][t][i] + rs[3][t][i];
      ps[((size_t)b * 64 + ntile) * 64 + t * 16 + i] = S;
    }
  }
}

// ---------------- k3: partial_q[b,k,c] = sum_{n in q} P[n,k] * x[b,n,c] ------------
// R14-proven core (dbuf LDS, one soft barrier per chunk). NEW: ct is the
// fastest-varying block index -> the 16 blocks sharing one P-range (128KB) and
// jointly tiling complete x rows are dispatched consecutively (L3 line sharing;
// R13 showed 1.05GB fetch vs 420MB ideal).
#define CT 48    // c-columns per block
#define NCH 128  // n rows staged per chunk
#define NQ 4     // n-splits
#define BUFO (CT * 128)  // shorts per LDS buffer
__device__ __forceinline__ int swz(int c) {
  return ((((c >> 3) ^ c) & 7) << 4);  // byte-XOR within a 256B row
}
__global__ __launch_bounds__(256) void k3_tokens(
    const float* __restrict__ x, const short* __restrict__ P,
    float* __restrict__ part) {
  __shared__ short xs[2 * BUFO];  // 2 x (CT rows x 256 bytes)
  char* xsb = (char*)xs;
  const int blk = blockIdx.x;
  const int ct = blk & 15;         // fastest: 16 ct-blocks consecutive
  const int q = (blk >> 4) & 3;
  const int b = blk >> 6;
  const int tid = threadIdx.x;
  const int w = tid >> 6, l = tid & 63, g = l >> 4, i = l & 15;

  const float* xb = x + (size_t)b * Ndim * Cdim;
  const short* Pb = P + (size_t)b * (Ndim * Kdim);

  f32x4 acc[3] = {};

#define LOADX(ch, buf)                                                        \
  do {                                                                        \
    const int n0_ = (ch) * NCH;                                               \
    _Pragma("unroll") for (int uu = 0; uu < 3; ++uu) {                        \
      int u_ = tid + uu * 256;                                                \
      int n_ = u_ / 6, c8_ = u_ % 6;                                          \
      const f32x4* src_ =                                                     \
          (const f32x4*)(xb + (size_t)(n0_ + n_) * Cdim + ct * CT + c8_ * 8); \
      buf[uu][0] = src_[0];                                                   \
      buf[uu][1] = src_[1];                                                   \
    }                                                                         \
  } while (0)

#define LOADL(ch, lvb)                                                        \
  do {                                                                        \
    const int nb8_ = (ch) * 16;                                               \
    _Pragma("unroll") for (int ns = 0; ns < 4; ++ns) {                        \
      lvb[ns] = *(const s16x8*)(Pb + (size_t)(nb8_ + ns * 4 + g) * 512 +      \
                                (w * 16 + i) * 8);                            \
    }                                                                         \
  } while (0)

#define STORELDS(base, buf)                                                   \
  do {                                                                        \
    _Pragma("unroll") for (int uu = 0; uu < 3; ++uu) {                        \
      int u_ = tid + uu * 256;                                                \
      int n_ = u_ / 6, c8_ = u_ % 6;                                          \
      _Pragma("unroll") for (int e = 0; e < 8; ++e) {                         \
        int c_ = c8_ * 8 + e;                                                 \
        float fv_ = (e < 4) ? buf[uu][0][e] : buf[uu][1][e - 4];              \
        *(short*)(xsb + (base) + c_ * 256 + ((2 * n_) ^ swz(c_))) = f2bf(fv_);\
      }                                                                       \
    }                                                                         \
  } while (0)

#define COMPUTE(base, lvb)                                                    \
  do {                                                                        \
    _Pragma("unroll") for (int ns = 0; ns < 4; ++ns) {                        \
      _Pragma("unroll") for (int cs = 0; cs < 3; ++cs) {                      \
        const int c_ = cs * 16 + i;                                           \
        s16x8 bfr_ = *(const s16x8*)(xsb + (base) + c_ * 256 +                \
                                     ((ns * 64 + g * 16) ^ swz(c_)));         \
        acc[cs] = MFMA(lvb[ns], bfr_, acc[cs]);                               \
      }                                                                       \
    }                                                                         \
  } while (0)

#define SOFT_BARRIER()                                                        \
  do {                                                                        \
    asm volatile("s_waitcnt lgkmcnt(0)" ::: "memory");                        \
    __builtin_amdgcn_s_barrier();                                             \
    __builtin_amdgcn_sched_barrier(0);                                        \
  } while (0)

  f32x4 stA[3][2], stB[3][2];
  s16x8 lvA[4], lvB[4];

  const int ch0 = q * 8;  // 8 chunks of 128 n per block
  LOADX(ch0, stA);
  LOADL(ch0, lvA);
  LOADX(ch0 + 1, stB);
  LOADL(ch0 + 1, lvB);
  STORELDS(0, stA);
  SOFT_BARRIER();

  for (int c = 0; c < 8; c += 2) {
    if (c + 2 < 8) LOADX(ch0 + c + 2, stA);
    STORELDS(BUFO * 2, stB);
    COMPUTE(0, lvA);
    if (c + 2 < 8) LOADL(ch0 + c + 2, lvA);
    SOFT_BARRIER();
    if (c + 3 < 8) LOADX(ch0 + c + 3, stB);
    if (c + 2 < 8) STORELDS(0, stA);
    COMPUTE(BUFO * 2, lvB);
    if (c + 3 < 8) LOADL(ch0 + c + 3, lvB);
    SOFT_BARRIER();
  }

  float* pb = part + ((size_t)q * Bdim + b) * (Kdim * Cdim);
#pragma unroll
  for (int r = 0; r < 4; ++r) {
    const int k = w * 16 + g * 4 + r;
#pragma unroll
    for (int cs = 0; cs < 3; ++cs) {
      pb[(size_t)k * Cdim + ct * CT + cs * 16 + i] = acc[cs][r];
    }
  }
#undef LOADX
#undef LOADL
#undef STORELDS
#undef COMPUTE
#undef SOFT_BARRIER
}

// ---------------- k4: invd (folded k2b) + out = invd * sum_q part[q] ---------------
// One block per (b,k) row: wave 0 shfl-reduces the 64 psum tiles -> 1/S,
// then threads 0..191 write the 768-float row (f32x4).
#define QSTRIDE (Bdim * Kdim * Cdim / 4)  // f32x4 units per q-slice = 393216
__global__ __launch_bounds__(256) void k4_reduce(
    const float* __restrict__ part, const float* __restrict__ psum,
    float* __restrict__ out) {
  const int row = blockIdx.x;          // = b*64 + k
  const int b = row >> 6, k = row & 63;
  const int tid = threadIdx.x;
  __shared__ float sInv;
  if (tid < 64) {
    float S = psum[((size_t)b * 64 + tid) * 64 + k];
#pragma unroll
    for (int off = 32; off > 0; off >>= 1) S += __shfl_xor(S, off);
    if (tid == 0) sInv = 1.f / S;
  }
  __syncthreads();
  if (tid < 192) {
    const f32x4* p = (const f32x4*)(part + (size_t)row * Cdim);
    f32x4 s = p[tid] + p[tid + QSTRIDE] + p[tid + 2 * QSTRIDE] +
              p[tid + 3 * QSTRIDE];
    ((f32x4*)(out + (size_t)row * Cdim))[tid] = s * sInv;
  }
}

extern "C" void kernel_launch(void* const* d_in, const int* in_sizes, int n_in,
                              void* d_out, int out_size, void* d_ws, size_t ws_size,
                              hipStream_t stream) {
  const float* x = (const float*)d_in[0];
  const float* W = (const float*)d_in[1];
  float* out = (float*)d_out;
  char* ws = (char*)d_ws;

  short* Wb = (short*)ws;                                   // 96 KB (pad 128K)
  short* P = (short*)(ws + (1 << 17));                      // 16 MB bf16 exp-logits
  char* after = ws + (1 << 17) + (size_t)Bdim * Ndim * Kdim * 2;
  float* psum = (float*)after;                              // [32][64][64] tile sums
  float* part = psum + Bdim * 64 * 64;                      // [4][32][64][768] fp32

  hipLaunchKernelGGL(k0_wcvt, dim3(24), dim3(256), 0, stream, W, Wb);
  hipLaunchKernelGGL(k1_logits, dim3(Bdim * 64), dim3(256), 0, stream, x, Wb, P, psum);
  hipLaunchKernelGGL(k3_tokens, dim3(Bdim * 16 * NQ), dim3(256), 0, stream, x, P, part);
  hipLaunchKernelGGL(k4_reduce, dim3(Bdim * Kdim), dim3(256), 0, stream, part, psum, out);
}